// Round 9
// baseline (339.807 us; speedup 1.0000x reference)
//
#include <hip/hip_runtime.h>

// LiftSplatBEV: B=2, N=6, C=64, HF=112, WF=200, D=64, BEV 200x200
#define BB   2
#define NN   6
#define CCH  64
#define HFE  112
#define WFE  200
#define DDE  64
#define HWF  (HFE*WFE)      // 22400 feature pixels (= 350*64); /4 = 5600 float4 groups
#define HWF4 (HWF/4)
#define BEVH 200
#define BEVW 200
#define HWB  (BEVH*BEVW)    // 40000 BEV cells
#define NBINS (BB*HWB)      // 80000 (b,cell) bins
#define NBINS_PAD 81920     // 320*256
#define NSCANB (NBINS_PAD/256)  // 320
#define MAXENT (BB*NN*HWF*4)    // 1,075,200 max entries (4 per valid slot)
#define NCHUNK (MAXENT/64)      // 16800 64-entry chunks
#define ACC_ELEMS ((size_t)BB*HWB*CCH)   // channel-last [b*HWB+cell][c]

__device__ __forceinline__ float4 f4max(float4 a, float4 b) {
    return make_float4(fmaxf(a.x,b.x), fmaxf(a.y,b.y), fmaxf(a.z,b.z), fmaxf(a.w,b.w));
}

// ---------------- shared geometry (bug-faithful to reference) ----------------
struct Geo {
    int valid;
    int c00, c10, c01, c11;
    float w00, w10, w01, w11;
};

__device__ __forceinline__ Geo geo_compute(int bn, int p,
    const float* __restrict__ I_inv, const float* __restrict__ E_inv,
    const float* __restrict__ Vm)
{
    Geo g; g.valid = 0;
    // bug-faithful w-outer flatten: u = p/112, v = p%112
    const float u = (float)(p / HFE);
    const float v = (float)(p % HFE);
    const float* Ii = I_inv + bn * 9;
    const float* Ei = E_inv + bn * 16;
    float cx = Ii[0]*u + Ii[1]*v + Ii[2];
    float cy = Ii[3]*u + Ii[4]*v + Ii[5];
    float cz = Ii[6]*u + Ii[7]*v + Ii[8];
    float tx = Ei[3], ty = Ei[7], tz = Ei[11];
    float dx = Ei[0]*cx + Ei[1]*cy + Ei[2] *cz + tx;   // includes translation (bug-faithful)
    float dy = Ei[4]*cx + Ei[5]*cy + Ei[6] *cz + ty;
    float dz = Ei[8]*cx + Ei[9]*cy + Ei[10]*cz + tz;
    float s  = -tz / fmaxf(dz, 1e-6f);
    float ex = tx + dx * s;
    float ey = ty + dy * s;
    float prx = Vm[0]*ex + Vm[1]*ey + Vm[2];
    float pry = Vm[3]*ex + Vm[4]*ey + Vm[5];
    float prz = Vm[6]*ex + Vm[7]*ey + Vm[8];
    float den = fmaxf(prz, 1e-7f);
    float bx = prx / den, by = pry / den;
    // bug-faithful gx->px roundtrip, same association order as reference
    float gx = bx / (float)(BEVW-1) * 2.0f - 1.0f;
    float gy = by / (float)(BEVH-1) * 2.0f - 1.0f;
    float px = (gx + 1.0f) * (float)(BEVW-1) / 2.0f;
    float py = (gy + 1.0f) * (float)(BEVH-1) / 2.0f;
    float x0f = fminf(fmaxf(floorf(px), 0.0f), (float)(BEVW-1));
    float y0f = fminf(fmaxf(floorf(py), 0.0f), (float)(BEVH-1));
    float x1f = fminf(x0f + 1.0f, (float)(BEVW-1));
    float y1f = fminf(y0f + 1.0f, (float)(BEVH-1));
    // far-edge-degenerate slots cancel exactly in the fp64 np reference: skip
    if (x0f == x1f || y0f == y1f) return g;
    float wx0 = x1f - px, wx1 = px - x0f;
    float wy0 = y1f - py, wy1 = py - y0f;
    int x0 = (int)x0f, x1 = (int)x1f, y0 = (int)y0f, y1 = (int)y1f;
    g.c00 = y0*BEVW + x0;  g.w00 = wx0*wy0;
    g.c10 = y0*BEVW + x1;  g.w10 = wx1*wy0;
    g.c01 = y1*BEVW + x0;  g.w01 = wx0*wy1;
    g.c11 = y1*BEVW + x1;  g.w11 = wx1*wy1;
    g.valid = 1;
    return g;
}

// Wave-run aggregation: consecutive lanes holding the same cell form a run.
__device__ __forceinline__ void run_info(int cell, int lane,
                                         bool& leader, int& runlen, int& leadlane)
{
    int prev = __shfl_up(cell, 1);
    bool change = (lane == 0) || (cell != prev);
    unsigned long long bal = __ballot(change);
    unsigned long long below = bal & (~0ull >> (63 - lane));
    leadlane = 63 - __builtin_clzll(below);
    unsigned long long above = (lane == 63) ? 0ull : (bal >> (lane + 1));
    int next = (above == 0ull) ? 64 : (lane + 1 + __builtin_ffsll((long long)above) - 1);
    runlen = next - lane;
    leader = change && (cell >= 0);
}

// ---------------- fused prep: conf(f4) + feat transpose(f4, pipelined) + histogram ----
// Grid (88,12), block 256: p in [p0, p0+256) of camera bn.
// LDS = 64x65 tile (16.6 KB) + cpart (4 KB) = 20.7 KB -> 7 blocks/CU (occupancy fix).
__global__ __launch_bounds__(256) void prep_kernel(
    const float* __restrict__ feat,    // [12,64,22400]
    const float* __restrict__ depth,   // [12,64,22400]
    const float* __restrict__ I_inv, const float* __restrict__ E_inv,
    const float* __restrict__ Vm,
    float* __restrict__ feat_t,        // [12,22400,64]
    float* __restrict__ conf,          // [12,22400]
    int* __restrict__ counts)          // [NBINS_PAD]
{
    __shared__ float tile[64][65];     // stride 65: odd -> ~2-way max aliasing (free)
    __shared__ float4 cpart[4][64];

    const int bn   = blockIdx.y;
    const int p0   = blockIdx.x * 256;
    const int tid  = threadIdx.x, lane = tid & 63, wv = tid >> 6;
    const int c    = tid >> 2;         // 0..63: read channel / write pixel
    const int q    = tid & 3;

    // -- conf partials: lane = float4 pixel-group, wave = 16-plane set (16 indep f4 loads)
    const int gbase = blockIdx.x * 64;
    const bool gok  = (gbase + lane) < HWF4;
    float4 mx = make_float4(-1e30f, -1e30f, -1e30f, -1e30f);
    if (gok) {
        const float4* d4 = (const float4*)depth + (size_t)(bn * DDE + wv * 16) * HWF4 + gbase + lane;
        mx = d4[0];
#pragma unroll
        for (int d = 1; d < 16; ++d)
            mx = f4max(mx, d4[(size_t)d * HWF4]);
    }
    cpart[wv][lane] = mx;

    // -- transpose: 4 rounds of 64 px, software-pipelined global loads
    const float* fcam = feat   + (size_t)bn * CCH * HWF;
    float*       ocam = feat_t + (size_t)bn * HWF * CCH;

    float4 regs[4];
    if (p0 < HWF) {
#pragma unroll
        for (int i = 0; i < 4; ++i)
            regs[i] = *(const float4*)(fcam + (size_t)c * HWF + p0 + 4 * (q + 4 * i));
    }
#pragma unroll
    for (int r = 0; r < 4; ++r) {
        const int pbr = p0 + 64 * r;
        if (pbr < HWF) {
#pragma unroll
            for (int i = 0; i < 4; ++i) {
                const int pg = q + 4 * i;
                tile[4*pg+0][c] = regs[i].x;
                tile[4*pg+1][c] = regs[i].y;
                tile[4*pg+2][c] = regs[i].z;
                tile[4*pg+3][c] = regs[i].w;
            }
        }
        __syncthreads();
        // prefetch next round (hidden behind this round's LDS reads + stores)
        const int pbn = p0 + 64 * (r + 1);
        if (r < 3 && pbn < HWF) {
#pragma unroll
            for (int i = 0; i < 4; ++i)
                regs[i] = *(const float4*)(fcam + (size_t)c * HWF + pbn + 4 * (q + 4 * i));
        }
        if (r == 0 && wv == 0 && gok) {
            // conf finalize by wave 0 (overlaps other waves' work)
            float4 mm = f4max(f4max(cpart[0][lane], cpart[1][lane]),
                              f4max(cpart[2][lane], cpart[3][lane]));
            *(float4*)(conf + (size_t)bn * HWF + 4 * (gbase + lane)) = mm;
        }
        if (pbr < HWF) {
            const int px = c;
#pragma unroll
            for (int i = 0; i < 4; ++i) {
                const int cg = q + 4 * i;
                float4 o;
                o.x = tile[px][4*cg+0];
                o.y = tile[px][4*cg+1];
                o.z = tile[px][4*cg+2];
                o.w = tile[px][4*cg+3];
                *(float4*)(ocam + (size_t)(pbr + px) * CCH + 4 * cg) = o;
            }
        }
        __syncthreads();
    }

    // -- histogram with run-aggregated atomics
    const int p   = p0 + tid;
    const int inb = (p < HWF);
    Geo g = geo_compute(bn, inb ? p : HWF - 1, I_inv, E_inv, Vm);
    const int valid = inb && g.valid;
    const int base  = (bn / NN) * HWB;
    const int cells[4] = { valid ? base + g.c00 : -1, valid ? base + g.c10 : -1,
                           valid ? base + g.c01 : -1, valid ? base + g.c11 : -1 };
#pragma unroll
    for (int k = 0; k < 4; ++k) {
        bool leader; int runlen, leadlane;
        run_info(cells[k], lane, leader, runlen, leadlane);
        if (leader) atomicAdd(&counts[cells[k]], runlen);
    }
}

// D1: per-256-block exclusive scan of counts
__global__ __launch_bounds__(256) void scan1_kernel(
    const int* __restrict__ counts, int* __restrict__ offsets, int* __restrict__ bsum)
{
    __shared__ int tmp[256];
    const int t = threadIdx.x;
    const int i = blockIdx.x * 256 + t;
    int v = counts[i];
    tmp[t] = v; __syncthreads();
    for (int off = 1; off < 256; off <<= 1) {
        int x = (t >= off) ? tmp[t - off] : 0;
        __syncthreads();
        tmp[t] += x;
        __syncthreads();
    }
    offsets[i] = tmp[t] - v;
    if (t == 255) bsum[blockIdx.x] = tmp[255];
}

// D2+D3 merged: each block sums preceding block-sums itself, finalizes offsets+cursor.
__global__ __launch_bounds__(256) void scan3_kernel(
    int* __restrict__ offsets, const int* __restrict__ bsum, int* __restrict__ cursor)
{
    __shared__ int s[256];
    const int t = threadIdx.x;
    int part = 0;
    for (int i = t; i < blockIdx.x; i += 256) part += bsum[i];
    s[t] = part; __syncthreads();
    for (int off = 128; off > 0; off >>= 1) {
        if (t < off) s[t] += s[t + off];
        __syncthreads();
    }
    const int i = blockIdx.x * 256 + t;
    int v = offsets[i] + s[0];
    offsets[i] = v;
    cursor[i]  = v;
}

// E: place entries (lean), run-aggregated cursor atomics + contiguous run writes
__global__ __launch_bounds__(256) void place_kernel(
    const float* __restrict__ conf,
    const float* __restrict__ I_inv, const float* __restrict__ E_inv,
    const float* __restrict__ Vm,
    int* __restrict__ cursor, int* __restrict__ ebin, uint2* __restrict__ entries)
{
    const int bn = blockIdx.y;
    const int p  = blockIdx.x * blockDim.x + threadIdx.x;
    const int lane = threadIdx.x & 63;
    const int inb = (p < HWF);
    const int pp = inb ? p : HWF - 1;
    Geo g = geo_compute(bn, pp, I_inv, E_inv, Vm);
    const int valid = inb && g.valid;
    const int base = (bn / NN) * HWB;

    const float cf = conf[(size_t)bn * HWF + pp];
    const unsigned bnp = (unsigned)(bn * HWF + pp);
    const int   cells[4] = { valid ? base + g.c00 : -1, valid ? base + g.c10 : -1,
                             valid ? base + g.c01 : -1, valid ? base + g.c11 : -1 };
    const float ws[4] = { g.w00 * cf, g.w10 * cf, g.w01 * cf, g.w11 * cf };

#pragma unroll
    for (int k = 0; k < 4; ++k) {
        bool leader; int runlen, leadlane;
        run_info(cells[k], lane, leader, runlen, leadlane);
        int pos_leader = 0;
        if (leader) pos_leader = atomicAdd(&cursor[cells[k]], runlen);
        int pos = __shfl(pos_leader, leadlane) + (lane - leadlane);
        if (valid) {
            ebin[pos]    = cells[k];
            entries[pos] = make_uint2(bnp, __float_as_uint(ws[k]));
        }
    }
}

// F: segmented gather, one wave per 64-entry chunk, lane = channel, 8-deep MLP.
__global__ __launch_bounds__(256) void gather_seg_kernel(
    const int* __restrict__ ebin, const uint2* __restrict__ entries,
    const int* __restrict__ total_ptr,
    const float* __restrict__ feat_t, float* __restrict__ acc)
{
    const int lane = threadIdx.x & 63, wv = threadIdx.x >> 6;
    const int chunk = blockIdx.x * 4 + wv;
    const int total = *total_ptr;
    const int start = chunk * 64;
    if (start >= total) return;
    const int m = min(64, total - start);   // multiple of 4

    int myb = -1;
    uint2 mye = make_uint2(0u, 0u);
    if (lane < m) { myb = ebin[start + lane]; mye = entries[start + lane]; }

    float a = 0.0f;
    int j = 0;
    for (; j + 8 <= m; j += 8) {
        int bb[9]; unsigned xx[8], ww[8];
#pragma unroll
        for (int k = 0; k < 8; ++k) {
            bb[k] = __shfl(myb, j + k);
            xx[k] = (unsigned)__shfl((int)mye.x, j + k);
            ww[k] = (unsigned)__shfl((int)mye.y, j + k);
        }
        bb[8] = (j + 8 < 64) ? __shfl(myb, j + 8) : -2;
        float f[8];
#pragma unroll
        for (int k = 0; k < 8; ++k)
            f[k] = feat_t[(size_t)xx[k] * CCH + lane];   // 8 indep coalesced 256B loads
#pragma unroll
        for (int k = 0; k < 8; ++k) {
            a = fmaf(f[k], __uint_as_float(ww[k]), a);
            if (bb[k] != bb[k + 1]) { atomicAdd(&acc[(size_t)bb[k] * CCH + lane], a); a = 0.0f; }
        }
    }
    if (j < m) {   // 4-entry tail
        int bb[5]; unsigned xx[4], ww[4];
#pragma unroll
        for (int k = 0; k < 4; ++k) {
            bb[k] = __shfl(myb, j + k);
            xx[k] = (unsigned)__shfl((int)mye.x, j + k);
            ww[k] = (unsigned)__shfl((int)mye.y, j + k);
        }
        bb[4] = (j + 4 < 64) ? __shfl(myb, j + 4) : -2;
        float f[4];
#pragma unroll
        for (int k = 0; k < 4; ++k)
            f[k] = feat_t[(size_t)xx[k] * CCH + lane];
#pragma unroll
        for (int k = 0; k < 4; ++k) {
            a = fmaf(f[k], __uint_as_float(ww[k]), a);
            if (bb[k] != bb[k + 1]) { atomicAdd(&acc[(size_t)bb[k] * CCH + lane], a); a = 0.0f; }
        }
    }
}

// G: out[b][c][cell] = acc[b*HWB+cell][c] / 6 -- float4 both sides via LDS tile
__global__ __launch_bounds__(256) void finalize_kernel(
    const float* __restrict__ acc, float* __restrict__ out)
{
    __shared__ float t[64][65];
    const int b     = blockIdx.y;
    const int cell0 = blockIdx.x * 64;
    const int cc    = threadIdx.x >> 2;   // read: cell row / write: channel
    const int q     = threadIdx.x & 3;

    const float* abase = acc + ((size_t)b * HWB + cell0) * CCH;
#pragma unroll
    for (int i = 0; i < 4; ++i) {
        const int cg = q + 4 * i;
        float4 f = *(const float4*)(abase + (size_t)cc * CCH + 4 * cg);
        t[cc][4*cg+0] = f.x; t[cc][4*cg+1] = f.y;
        t[cc][4*cg+2] = f.z; t[cc][4*cg+3] = f.w;
    }
    __syncthreads();
    float* obase = out + (size_t)b * CCH * HWB + cell0;
#pragma unroll
    for (int i = 0; i < 4; ++i) {
        const int lg = q + 4 * i;           // cell-group
        float4 o;
        o.x = t[4*lg+0][cc] * (1.0f/6.0f);
        o.y = t[4*lg+1][cc] * (1.0f/6.0f);
        o.z = t[4*lg+2][cc] * (1.0f/6.0f);
        o.w = t[4*lg+3][cc] * (1.0f/6.0f);
        *(float4*)(obase + (size_t)cc * HWB + 4 * lg) = o;
    }
}

// ---------------- fallback (round-4 atomic splat) if ws too small ----------------
__global__ __launch_bounds__(256) void splat_kernel(
    const float* __restrict__ feat, const float* __restrict__ depth,
    const float* __restrict__ I_inv, const float* __restrict__ E_inv,
    const float* __restrict__ Vm, float* __restrict__ acc)
{
    __shared__ float fshare[64][65];
    __shared__ float cpart2[4][64];
    const int bn = blockIdx.y, b = bn / NN, p0 = blockIdx.x * 64;
    const int lane = threadIdx.x & 63, wv = threadIdx.x >> 6;
    const float* fbase = feat + (size_t)bn * CCH * HWF + p0;
#pragma unroll
    for (int c = wv; c < CCH; c += 4)
        fshare[lane][c] = fbase[(size_t)c * HWF + lane];
    const float* dbase = depth + (size_t)bn * DDE * HWF + p0;
    float m = dbase[(size_t)(wv * 16) * HWF + lane];
#pragma unroll
    for (int d = wv * 16 + 1; d < wv * 16 + 16; ++d)
        m = fmaxf(m, dbase[(size_t)d * HWF + lane]);
    cpart2[wv][lane] = m;
    __syncthreads();
    float* ab = acc + ((size_t)b * HWB) * CCH + lane;
    for (int s = wv * 16; s < wv * 16 + 16; ++s) {
        Geo g = geo_compute(bn, p0 + s, I_inv, E_inv, Vm);
        if (!g.valid) continue;
        float cf = fmaxf(fmaxf(cpart2[0][s], cpart2[1][s]), fmaxf(cpart2[2][s], cpart2[3][s]));
        float f = fshare[s][lane];
        atomicAdd(ab + (size_t)g.c00 * CCH, f * (g.w00 * cf));
        atomicAdd(ab + (size_t)g.c10 * CCH, f * (g.w10 * cf));
        atomicAdd(ab + (size_t)g.c01 * CCH, f * (g.w01 * cf));
        atomicAdd(ab + (size_t)g.c11 * CCH, f * (g.w11 * cf));
    }
}

extern "C" void kernel_launch(void* const* d_in, const int* in_sizes, int n_in,
                              void* d_out, int out_size, void* d_ws, size_t ws_size,
                              hipStream_t stream) {
    const float* feat  = (const float*)d_in[0];
    const float* depth = (const float*)d_in[1];
    const float* I_inv = (const float*)d_in[2];
    const float* E_inv = (const float*)d_in[3];
    const float* Vm    = (const float*)d_in[4];
    float* out = (float*)d_out;

    size_t off = 0;
    char* wsb = (char*)d_ws;
    auto carve = [&](size_t bytes) -> void* {
        void* p = wsb + off; off += (bytes + 255) & ~(size_t)255; return p;
    };
    // acc and counts adjacent -> single memset (acc bytes are 256B-multiple)
    float* feat_t  = (float*)carve((size_t)BB * NN * CCH * HWF * 4);  // 68.8 MB
    float* acc     = (float*)carve(ACC_ELEMS * 4);                    // 20.5 MB
    int*   counts  = (int*)  carve((NBINS_PAD + 256) * 4);            // 0.33 MB
    uint2* entries = (uint2*)carve((size_t)MAXENT * 8);               //  8.6 MB
    int*   ebin    = (int*)  carve((size_t)MAXENT * 4);               //  4.3 MB
    float* conf    = (float*)carve((size_t)BB * NN * HWF * 4);        //  1.1 MB
    int*   offsets = (int*)  carve((NBINS_PAD + 256) * 4);
    int*   cursor  = (int*)  carve((NBINS_PAD + 256) * 4);
    int*   bsum    = (int*)  carve(NSCANB * 4);

    if (off <= ws_size) {
        hipMemsetAsync(acc, 0, ACC_ELEMS * 4 + (NBINS_PAD + 256) * 4, stream);

        dim3 pgrid((HWF + 255) / 256, BB * NN);        // (88,12)
        prep_kernel<<<pgrid, 256, 0, stream>>>(feat, depth, I_inv, E_inv, Vm,
                                               feat_t, conf, counts);

        scan1_kernel<<<NSCANB, 256, 0, stream>>>(counts, offsets, bsum);
        scan3_kernel<<<NSCANB, 256, 0, stream>>>(offsets, bsum, cursor);

        place_kernel<<<pgrid, 256, 0, stream>>>(conf, I_inv, E_inv, Vm,
                                                cursor, ebin, entries);

        gather_seg_kernel<<<NCHUNK / 4, 256, 0, stream>>>(
            ebin, entries, offsets + NBINS, feat_t, acc);

        dim3 fgrid(HWB / 64, BB);                      // (625,2)
        finalize_kernel<<<fgrid, 256, 0, stream>>>(acc, out);
    } else {
        float* acc0 = (float*)d_ws;
        hipMemsetAsync(acc0, 0, ACC_ELEMS * 4, stream);
        dim3 grid(HWF / 64, BB * NN);
        splat_kernel<<<grid, 256, 0, stream>>>(feat, depth, I_inv, E_inv, Vm, acc0);
        dim3 fgrid(HWB / 64, BB);
        finalize_kernel<<<fgrid, 256, 0, stream>>>(acc0, out);
    }
}